// Round 2
// baseline (373.884 us; speedup 1.0000x reference)
//
#include <hip/hip_runtime.h>
#include <stdint.h>

#define NUM_UNIQUE   256
#define NUM_SAMPLES  4096
#define NUM_QUBITS   64
#define BATCH_SIZE   1024

#define THREADS      256
#define WAVES        4                         // waves per block
#define BLOCKS_PER_C 4                         // blocks per unique circuit
#define GRID         (NUM_UNIQUE * BLOCKS_PER_C)
#define CHUNKS_PER_WAVE 4                      // 64 chunks / (4 blocks * 4 waves)
#define CHUNK_V4     1024                      // v4i per 64-sample chunk (64*64*4B / 16B)

typedef int v4i __attribute__((ext_vector_type(4)));
typedef unsigned long long u64;

// R5 = R4 + race fix:
//  R4's ring Gram reads words[wave][lane+d] (d=1..32) while writing lane and
//  lane+64 — per-thread provably non-aliasing, so the compiler may reorder
//  the ds_reads across the ds_writes; the cross-lane dependency (lane q needs
//  lane q+d's CURRENT-chunk write) is invisible to it. Stale B_r -> absmax 0.43.
//  Fix: asm memory fences on both sides of the ring writes. LDS is in-order
//  per wave in hardware, so compile-time ordering is sufficient; no
//  __syncthreads (that would s_waitcnt vmcnt(0) and drain the chunk prefetch).
//  Pipeline preserved: chunk ci+1 loads are issued before iteration ci's
//  fences, one full Gram loop ahead of consumption.
__global__ __launch_bounds__(THREADS, 4)
void energy_kernel(const int* __restrict__ samples,
                   const float* __restrict__ bias,
                   const float* __restrict__ Kmat,
                   float* __restrict__ part)     // [GRID] partial sums
{
    __shared__ float Klds[NUM_QUBITS * 65];      // +1 pad: 2-way = free
    __shared__ float KS[NUM_QUBITS * 33];        // Ksym rows, pad 33
    __shared__ u64   words[WAVES][128];          // per-wave, duplicated ring
    __shared__ float wsum[WAVES];

    const int tid  = threadIdx.x;
    const int wave = tid >> 6;
    const int lane = tid & 63;
    const int blk  = blockIdx.x;
    const int c    = blk >> 2;
    const int sub  = blk & 3;

    // this wave's 4 consecutive chunks of 64 samples
    const int chunk0 = sub * 16 + wave * CHUNKS_PER_WAVE;
    const v4i* cp = (const v4i*)samples
                  + (size_t)c * (NUM_SAMPLES * NUM_QUBITS / 4)
                  + (size_t)chunk0 * CHUNK_V4;

    // issue chunk 0's loads before K staging so they fly under the setup
    v4i L[16];
    #pragma unroll
    for (int i = 0; i < 16; ++i)
        L[i] = __builtin_nontemporal_load(cp + i * 64 + lane);

    for (int t = tid; t < NUM_QUBITS * NUM_QUBITS; t += THREADS)
        Klds[(t >> 6) * 65 + (t & 63)] = Kmat[t];
    __syncthreads();

    // Ksym[q][d] = K[q][(q+d)&63] + K[(q+d)&63][q], d=1..32 (d=32 pairs double-
    // enumerated around the ring -> 0.5 weight)
    for (int t = tid; t < 64 * 32; t += THREADS) {
        int q = t >> 5, d = (t & 31) + 1, r = (q + d) & 63;
        float v = Klds[q * 65 + r] + Klds[r * 65 + q];
        KS[q * 33 + d] = (d == 32) ? 0.5f * v : v;
    }

    float rowsum = 0.0f;
    {
        const float* Krow = &Klds[lane * 65];
        #pragma unroll
        for (int r = 0; r < 64; ++r) rowsum += Krow[r];
    }
    __syncthreads();

    const float* ks = &KS[lane * 33];            // ks[d], imm offsets
    u64* wrow       = &words[wave][0];
    const u64* wp   = &words[wave][lane];        // wp[d] = B_{(lane+d)&63}

    float pcacc = 0.0f;   // sum over chunks,pairs of Ksym * popcount(B_q^B_r)
    int   cnt   = 0;      // ones of qubit `lane` over this wave's 256 samples

    #pragma unroll
    for (int ci = 0; ci < CHUNKS_PER_WAVE; ++ci) {
        // ---- pack current chunk (consumes L) ----
        unsigned int m0 = 0, m1 = 0, m2 = 0, m3 = 0;
        #pragma unroll
        for (int i = 0; i < 16; ++i) {
            v4i v = L[i];
            m0 = (m0 << 1) | (unsigned int)(v.x & 1);
            m1 = (m1 << 1) | (unsigned int)(v.y & 1);
            m2 = (m2 << 1) | (unsigned int)(v.z & 1);
            m3 = (m3 << 1) | (unsigned int)(v.w & 1);
        }

        // ---- issue next chunk's loads NOW: in flight during transpose+Gram ----
        if (ci + 1 < CHUNKS_PER_WAVE) {
            const v4i* np = cp + (size_t)(ci + 1) * CHUNK_V4;
            #pragma unroll
            for (int i = 0; i < 16; ++i)
                L[i] = __builtin_nontemporal_load(np + i * 64 + lane);
        }

        u64 W = (u64)m0 | ((u64)m1 << 16) | ((u64)m2 << 32) | ((u64)m3 << 48);

        // ---- 4-step shuffle transpose: lane q ends with bitmask B_q ----
        u64 B = 0ull;
        #pragma unroll
        for (int p = 0; p < 4; ++p) {
            u64 src = __shfl(W, 16 * p + (lane >> 2));
            B |= ((src >> (16 * (lane & 3))) & 0xFFFFull) << (16 * p);
        }

        cnt += (int)__popcll(B);

        // ---- ring publish: fence both sides so ds_reads of THIS chunk can
        // neither hoist above these writes nor can next chunk's writes sink
        // below this chunk's reads (per-thread alias analysis can't see the
        // cross-lane dependency). LDS is in-order per wave in HW.
        asm volatile("" ::: "memory");
        wrow[lane]      = B;
        wrow[lane + 64] = B;                     // ring duplicate: base+imm reads
        asm volatile("" ::: "memory");

        // ---- symmetric Gram: 32 ring pairs instead of 64 rows ----
        #pragma unroll
        for (int d = 1; d <= 32; ++d) {
            u64 br = wp[d];
            int pc = (int)__popcll(B ^ br);
            pcacc = fmaf(ks[d], (float)pc, pcacc);
        }
    }

    // quad: sum_s s^T K s = 64*nchunk*sum(K) - 2*sum_pairs Ksym*pc
    // linear: bias_q * sum_s s_q = bias_q * (256 - 2*cnt)
    float contrib = 64.0f * (float)CHUNKS_PER_WAVE * rowsum - 2.0f * pcacc
                  + bias[lane] * (float)(CHUNKS_PER_WAVE * 64 - 2 * cnt);

    #pragma unroll
    for (int off = 32; off > 0; off >>= 1)
        contrib += __shfl_down(contrib, off);

    if (lane == 0) wsum[wave] = contrib;
    __syncthreads();
    if (tid == 0)
        part[blk] = wsum[0] + wsum[1] + wsum[2] + wsum[3];
}

__global__ void gather_kernel(const float* __restrict__ part,
                              const int* __restrict__ idx,
                              float* __restrict__ out)
{
    int b = blockIdx.x * blockDim.x + threadIdx.x;
    if (b < BATCH_SIZE) {
        int u = idx[b] << 2;
        out[b] = (part[u] + part[u + 1] + part[u + 2] + part[u + 3])
               * (1.0f / NUM_SAMPLES);
    }
}

extern "C" void kernel_launch(void* const* d_in, const int* in_sizes, int n_in,
                              void* d_out, int out_size, void* d_ws, size_t ws_size,
                              hipStream_t stream)
{
    const int*   samples = (const int*)d_in[0];
    const int*   idx     = (const int*)d_in[1];
    const float* bias    = (const float*)d_in[2];
    const float* Kmat    = (const float*)d_in[3];
    float* out  = (float*)d_out;
    float* part = (float*)d_ws;   // GRID floats of scratch

    energy_kernel<<<GRID, THREADS, 0, stream>>>(samples, bias, Kmat, part);
    gather_kernel<<<(BATCH_SIZE + THREADS - 1) / THREADS, THREADS, 0, stream>>>(part, idx, out);
}

// Round 3
// 340.416 us; speedup vs baseline: 1.0983x; 1.0983x over previous
//
#include <hip/hip_runtime.h>
#include <stdint.h>

#define NUM_UNIQUE   256
#define NUM_SAMPLES  4096
#define NUM_QUBITS   64
#define BATCH_SIZE   1024
#define THREADS      1024
#define WAVES        (THREADS / 64)
#define CHUNKS       (NUM_SAMPLES / 64)      // 64 chunks of 64 samples
#define CHUNKS_PER_WAVE (CHUNKS / WAVES)     // 4

typedef int v4i __attribute__((ext_vector_type(4)));
typedef unsigned long long u64;

// R6 = R3 chassis (349 µs measured: 1024-thread blocks, one block per circuit,
// convoy-breaking loadrot/chunkrot, load-and-consume staging — NO register
// prefetch buffer; R5 showed 16 waves/CU of TLP already covers HBM latency and
// the L[16] buffer only added VGPR pressure)
//   + symmetric Gram from R5 (verified, absmax 1.9e-6): ring d=1..32 over
//     Ksym[q][d] = K[q][(q+d)&63] + K[(q+d)&63][q] (0.5x at d=32). Halves Gram
//     LDS reads (128->64/chunk) and Gram VALU (~384->~192/chunk). Fences pin
//     the ring publish (cross-lane dep invisible to per-thread alias analysis).
//   + fused gather: block c broadcasts its mean, thread b writes out[b] iff
//     idx[b]==c (each b matches exactly one c). One dispatch, zero ws use.
__global__ __launch_bounds__(THREADS)
void energy_kernel(const int* __restrict__ samples,
                   const int* __restrict__ idx,
                   const float* __restrict__ bias,
                   const float* __restrict__ Kmat,
                   float* __restrict__ out)
{
    __shared__ float Klds[NUM_QUBITS * 65];      // +1 pad: 2-way = free
    __shared__ float KS[NUM_QUBITS * 33];        // Ksym rows, pad 33: 2-way = free
    __shared__ u64   words[WAVES][128];          // per-wave duplicated ring
    __shared__ float wsum[WAVES];
    __shared__ float uval;

    const int tid  = threadIdx.x;
    const int wave = tid >> 6;
    const int lane = tid & 63;
    const int c    = blockIdx.x;

    for (int t = tid; t < NUM_QUBITS * NUM_QUBITS; t += THREADS)
        Klds[(t >> 6) * 65 + (t & 63)] = Kmat[t];
    __syncthreads();

    // Ksym fold (d=32 pairs enumerated twice around the ring -> 0.5 weight)
    for (int t = tid; t < 64 * 32; t += THREADS) {
        int q = t >> 5, d = (t & 31) + 1, r = (q + d) & 63;
        float v = Klds[q * 65 + r] + Klds[r * 65 + q];
        KS[q * 33 + d] = (d == 32) ? 0.5f * v : v;
    }

    float rowsum = 0.0f;
    {
        const float* Krow = &Klds[lane * 65];
        #pragma unroll
        for (int r = 0; r < 64; ++r) rowsum += Krow[r];
    }
    __syncthreads();                             // KS ready

    const float* ks = &KS[lane * 33];            // ks[d], base + imm offsets
    u64* wrow       = &words[wave][0];
    const u64* wp   = &words[wave][lane];        // wp[d] = B_{(lane+d)&63}

    float pcacc = 0.0f;   // sum over chunks,pairs of Ksym * popcount(B_q^B_r)
    int   cnt   = 0;      // ones of qubit `lane` over this wave's 256 samples

    const int loadrot  = (3 * wave + 5 * c) & 15;   // intra-chunk phase stagger
    const int chunkrot = (13 * c) & 63;             // chunk-order stagger

    for (int ci = 0; ci < CHUNKS_PER_WAVE; ++ci) {
        const int chunk = ((wave * CHUNKS_PER_WAVE + ci) + chunkrot) & 63;
        const v4i* cp = (const v4i*)(samples +
            ((size_t)c * NUM_SAMPLES + (size_t)chunk * 64) * NUM_QUBITS);

        // ---- coalesced, phase-staggered load + bit pack (R3 verbatim) ----
        // iter i loads slice j=(i+loadrot)&15: concurrent wave-instrs across
        // the device spread over the 16 KB chunk instead of channel lockstep.
        // The permutation is wave-uniform, so popcounts are unaffected.
        unsigned int m0 = 0, m1 = 0, m2 = 0, m3 = 0;
        #pragma unroll
        for (int i = 0; i < 16; ++i) {
            const int j = (i + loadrot) & 15;
            v4i v = __builtin_nontemporal_load(cp + j * 64 + lane);
            m0 = (m0 << 1) | (unsigned int)(v.x & 1);
            m1 = (m1 << 1) | (unsigned int)(v.y & 1);
            m2 = (m2 << 1) | (unsigned int)(v.z & 1);
            m3 = (m3 << 1) | (unsigned int)(v.w & 1);
        }
        u64 W = (u64)m0 | ((u64)m1 << 16) | ((u64)m2 << 32) | ((u64)m3 << 48);

        // ---- 4-step shuffle transpose: lane q ends with bitmask B_q ----
        u64 B = 0ull;
        #pragma unroll
        for (int p = 0; p < 4; ++p) {
            u64 src = __shfl(W, 16 * p + (lane >> 2));
            B |= ((src >> (16 * (lane & 3))) & 0xFFFFull) << (16 * p);
        }

        cnt += (int)__popcll(B);

        // ---- fenced ring publish: ds_reads of THIS chunk must not hoist
        // above these writes (per-thread alias analysis can't see the
        // cross-lane dep). LDS is in-order per wave in HW; compile-time
        // ordering suffices — no barrier, no waitcnt drain.
        asm volatile("" ::: "memory");
        wrow[lane]      = B;
        wrow[lane + 64] = B;                     // duplicate: reads are base+imm
        asm volatile("" ::: "memory");

        // ---- symmetric Gram: 32 ring pairs instead of 64 rows ----
        #pragma unroll
        for (int d = 1; d <= 32; ++d) {
            u64 br = wp[d];
            int pc = (int)__popcll(B ^ br);
            pcacc = fmaf(ks[d], (float)pc, pcacc);
        }
    }

    // quad: sum_s s^T K s = 64*nchunk*sum(K) - 2*sum_pairs Ksym*pc
    // linear: bias_q * sum_s s_q = bias_q * (256 - 2*cnt)
    float contrib = 64.0f * (float)CHUNKS_PER_WAVE * rowsum - 2.0f * pcacc
                  + bias[lane] * (float)(CHUNKS_PER_WAVE * 64 - 2 * cnt);

    #pragma unroll
    for (int off = 32; off > 0; off >>= 1)
        contrib += __shfl_down(contrib, off);

    if (lane == 0) wsum[wave] = contrib;
    __syncthreads();
    if (tid == 0) {
        float s = 0.0f;
        #pragma unroll
        for (int i = 0; i < WAVES; ++i) s += wsum[i];
        uval = s * (1.0f / NUM_SAMPLES);
    }
    __syncthreads();

    // ---- fused expand_unique_results: thread b handles batch entry b ----
    const float u = uval;
    if (idx[tid] == c) out[tid] = u;
}

extern "C" void kernel_launch(void* const* d_in, const int* in_sizes, int n_in,
                              void* d_out, int out_size, void* d_ws, size_t ws_size,
                              hipStream_t stream)
{
    const int*   samples = (const int*)d_in[0];
    const int*   idx     = (const int*)d_in[1];
    const float* bias    = (const float*)d_in[2];
    const float* Kmat    = (const float*)d_in[3];
    float* out = (float*)d_out;

    energy_kernel<<<NUM_UNIQUE, THREADS, 0, stream>>>(samples, idx, bias, Kmat, out);
}